// Round 3
// baseline (1111.113 us; speedup 1.0000x reference)
//
#include <hip/hip_runtime.h>
#include <hip/hip_bf16.h>

// ---------------------------------------------------------------------------
// Qwen2VL SDPA attention block, MI355X/gfx950. fp32 in/out, bf16 MFMA inside.
// T=4096, D=1280, H=16, HD=80, 8 segments of 512 (block-diagonal attention).
// Pipeline: [C]  convert hidden/qkv_w/proj_w fp32->bf16 (one fused kernel)
//           [K1] qkv GEMM (128x160 tile, dbuf global_load_lds) with FUSED
//                ROPE epilogue -> Qh/Kh [h][t][96], V -> Vt[h][d][t]
//           [K3] attention: K/V DMA double-buffered, exact softmax
//           [K4] out = attn @ proj_w^T + proj_b (BM=64, A-sharing XCD swizzle)
// R1: chunk XOR-swizzle on all staging/frag paths -> bank conflicts 4.4M -> 0.
//     Only -4% => not conflict-bound.
// R2: XCD mapping (FETCH 61->50 MB, at floor) + capacity 4/CU: time flat
//     => not HBM-bound, not TLP-starved. K1 is SCHEDULE-bound: the
//     __syncthreads vmcnt(0) drain per K-step (m233: 2-phase overhead ~72%).
// R3: counted-vmcnt K-loop (T3+T4 derived-waits port), shared by K1/K4:
//     per iter: [ds_read frags][lgkm0][sbar#1][stage(kt+2)][MFMA w/setprio]
//     [vmcnt(N) = newest batch stays in flight][sbar#2]. The wait targets the
//     PREVIOUS stage batch (issued one full iteration earlier, already
//     landed); no full drain anywhere in the main loop.
// ---------------------------------------------------------------------------

#define T_DIM 4096
#define D_DIM 1280
#define NH    16
#define HD    80
#define HDP   96      // head dim padded to 3x32 for K=32 MFMA steps
#define SEG   512
#define VLP   136     // P LDS row stride (pad off pow2)
#define RLS   80      // rope-epilogue LDS row stride (epilogue-only conflicts
                      // ~500 cyc once per block = noise; keeps LDS at 40960)

typedef __bf16 bf16;
typedef bf16  bf16x4 __attribute__((ext_vector_type(4)));
typedef bf16  bf16x8 __attribute__((ext_vector_type(8)));
typedef float f32x4  __attribute__((ext_vector_type(4)));

#define SBAR()    asm volatile("s_barrier" ::: "memory")
#define WAITVM(n) asm volatile("s_waitcnt vmcnt(" #n ")" ::: "memory")
#define WAITLG()  asm volatile("s_waitcnt lgkmcnt(0)" ::: "memory")
#define SCHEDB()  __builtin_amdgcn_sched_barrier(0)

__device__ __forceinline__ void gload16(const bf16* g, bf16* l) {
  __builtin_amdgcn_global_load_lds(
      (const __attribute__((address_space(1))) void*)g,
      (__attribute__((address_space(3))) void*)l, 16, 0, 0);
}

// ---------------------------------------------------------------------------
// Fused fp32->bf16 convert of hidden (1310720 f4), qkv_w (1228800 f4),
// proj_w (409600 f4). Grid covers 2949120 float4 groups.
// ---------------------------------------------------------------------------
__global__ __launch_bounds__(256) void cvt_all(
    const float* __restrict__ hid, const float* __restrict__ qw,
    const float* __restrict__ pw, bf16* __restrict__ hb,
    bf16* __restrict__ qwb, bf16* __restrict__ pwb)
{
  int i = blockIdx.x * 256 + threadIdx.x;
  const float* src; bf16* dst; int off;
  if (i < 1310720)      { src = hid; dst = hb;  off = i; }
  else if (i < 2539520) { src = qw;  dst = qwb; off = i - 1310720; }
  else                  { src = pw;  dst = pwb; off = i - 2539520; }
  float4 v = ((const float4*)src)[off];
  ((bf16x4*)dst)[off] = (bf16x4){(bf16)v.x, (bf16)v.y, (bf16)v.z, (bf16)v.w};
}

// ---------------------------------------------------------------------------
// BMxBN-tile GEMM: C = A[M,K] @ W[N,K]^T + bias. BK=32, 4 waves (2x2), each
// wave (BM/2)x(BN/2). Double-buffered LDS via global_load_lds width=16.
// LDS rows are 32 bf16 (64 B = 4 chunks of 16 B); chunk c of row r holds
// logical chunk c ^ ((r>>1)&3)  [staged via pre-swizzled global source,
// deswizzled on the frag read]  -> 2-way banks instead of 8-way.
// K-loop: counted-vmcnt derived-waits schedule (see header R3).
// EPI=0 (BM=128,BN=160): wave-half = exactly one head. Q/K tiles: C-tile ->
//   wave-private LDS -> per-row rope (pairs (d,d+40) in-row) -> [h][t][96]
//   with zeroed pads, row chunks XOR-swizzled by ((t>>1)&3). V tiles:
//   Vt[h][d][T] bf16x4 scatter. Grid: mt=lin/24, nt=lin%24 (XCD = nt%8).
// EPI=1: A-sharing swizzle (lin%8==mt%8 -> one XCD per A-tile); fp32 store.
// ---------------------------------------------------------------------------
template <int EPI, int BM, int BN>
__global__ __launch_bounds__(256, 4) void gemm128(
    const bf16* __restrict__ A, const bf16* __restrict__ W,
    const float* __restrict__ bias, const float* __restrict__ rot,
    void* __restrict__ out0, bf16* __restrict__ Kh, bf16* __restrict__ Vt,
    int N, int K, int tiles_n)
{
  constexpr int MI = BM / 32;               // m-frags per wave
  constexpr int NJ = BN / 32;               // n-frags per wave
  constexpr int STAGE = 2 * (BM + BN) * 32;
  constexpr int EPIB  = (EPI == 0) ? 4 * 64 * RLS : 0;
  constexpr int LDSZ  = (STAGE > EPIB ? STAGE : EPIB);
  __shared__ __align__(16) bf16 smem[LDSZ];
  bf16* As = smem;
  bf16* Bs = smem + 2 * BM * 32;

  int tid  = threadIdx.x;
  int wave = tid >> 6, lane = tid & 63;
  int l15 = lane & 15, quad = lane >> 4;
  // deswizzled chunk offset for frag reads: row bits1..2 == l15 bits1..2
  int q8s = ((quad ^ ((l15 >> 1) & 3)) * 8);
  int mt, nt;
  if (EPI == 0) {
    // XCD-locality mapping: lin = mt*tiles_n + nt, tiles_n % 8 == 0
    // => XCD(lin%8) = nt%8: same-W blocks co-located, W-tile L2-resident.
    mt = blockIdx.x / tiles_n;
    nt = blockIdx.x % tiles_n;
  } else {
    // A-sharing swizzle: lin = nt*tiles_m + mt -> lin%8 == mt%8 (same XCD)
    int tiles_m = gridDim.x / tiles_n;
    mt = blockIdx.x % tiles_m;
    nt = blockIdx.x / tiles_m;
  }
  int m0 = mt * BM, n0 = nt * BN;
  int wm = (wave >> 1) * (BM / 2), wn = (wave & 1) * (BN / 2);

  int er  = tid >> 2;
  // source chunk XOR-pre-swizzle: LDS dest (tid*16B) is linear, so physical
  // chunk (tid&3) of row er must hold logical chunk (tid&3)^((er>>1)&3).
  int ec8 = (((tid & 3) ^ ((tid >> 3) & 3)) * 8);
  const bf16* ga = A + (size_t)(m0 + er) * K + ec8;
  const bf16* gb = W + (size_t)(n0 + er) * K + ec8;

  auto issue = [&](int k, int p) {
    bf16* la = As + p * (BM * 32) + tid * 8;
    bf16* lb = Bs + p * (BN * 32) + tid * 8;
#pragma unroll
    for (int i = 0; i < BM / 64; ++i) gload16(ga + (size_t)i * 64 * K + k, la + i * 2048);
#pragma unroll
    for (int i = 0; i < BN / 64; ++i) gload16(gb + (size_t)i * 64 * K + k, lb + i * 2048);
  };

  f32x4 acc[MI][NJ];
#pragma unroll
  for (int i = 0; i < MI; ++i)
#pragma unroll
    for (int j = 0; j < NJ; ++j) acc[i][j] = (f32x4){0.f, 0.f, 0.f, 0.f};

  // staging for BN=160: B has 160 rows => threads 0..255 do two chunks,
  // threads 0..127 do a third (rows 128..159). Per-wave load counts:
  // waves 0,1: 5 instrs; waves 2,3: 4. (EPI=1: uniform 3.)
  auto issue160 = [&](int k, int p) {
    bf16* la = As + p * (BM * 32) + tid * 8;
    bf16* lb = Bs + p * (BN * 32) + tid * 8;
    gload16(ga + k, la);
    gload16(ga + (size_t)64 * K + k, la + 2048);
    gload16(gb + k, lb);
    gload16(gb + (size_t)64 * K + k, lb + 2048);
    if (tid < 128) gload16(gb + (size_t)128 * K + k, lb + 4096);
  };
  auto issueN = [&](int k, int p) {
    if (BN == 160) issue160(k, p);
    else           issue(k, p);
  };
  // wait leaving exactly one stage batch (the newest) in flight
  auto waitN = [&]() {
    if (BN == 160) { if (wave < 2) { WAITVM(5); } else { WAITVM(4); } }
    else           { WAITVM(3); }
    SCHEDB();
  };

  int NK = K / 32;
  // prologue: stage tiles 0 and 1; wait own stage(0) batch; align waves
  issueN(0, 0);
  issueN(32, 1);
  waitN();
  SBAR();

  for (int kt = 0; kt < NK; ++kt) {
    int p = kt & 1;
    bf16x8 af[MI], bfr[NJ];
#pragma unroll
    for (int i = 0; i < MI; ++i)
      af[i] = *(const bf16x8*)(As + p * (BM * 32) + (wm + i * 16 + l15) * 32 + q8s);
#pragma unroll
    for (int j = 0; j < NJ; ++j)
      bfr[j] = *(const bf16x8*)(Bs + p * (BN * 32) + (wn + j * 16 + l15) * 32 + q8s);
    if (kt < NK - 1) {
      WAITLG();                            // my frag reads are in VGPRs
      SCHEDB();
      SBAR();                              // #1: all waves done reading buf[p]
      if (kt + 2 < NK) issueN((kt + 2) * 32, p);   // overwrite buf[p]
      __builtin_amdgcn_s_setprio(1);
#pragma unroll
      for (int i = 0; i < MI; ++i)
#pragma unroll
        for (int j = 0; j < NJ; ++j)
          acc[i][j] = __builtin_amdgcn_mfma_f32_16x16x32_bf16(af[i], bfr[j], acc[i][j], 0, 0, 0);
      __builtin_amdgcn_s_setprio(0);
      if (kt + 2 < NK) waitN();            // stage(kt+1) retired; newest flies
      else             { WAITVM(0); SCHEDB(); }
      SBAR();                              // #2: tile kt+1 ready for all
    } else {
#pragma unroll
      for (int i = 0; i < MI; ++i)
#pragma unroll
        for (int j = 0; j < NJ; ++j)
          acc[i][j] = __builtin_amdgcn_mfma_f32_16x16x32_bf16(af[i], bfr[j], acc[i][j], 0, 0, 0);
    }
  }

  if (EPI == 0) {
    bf16* Qh = (bf16*)out0;
    int c0  = n0 + wn;                 // wave's first col = head base
    int sel = c0 / D_DIM;              // 0=Q, 1=K, 2=V (block-uniform: BN=160 | 1280)
    if (sel < 2) {
      // ---- fused rope epilogue ----
      __syncthreads();                 // all frag reads done; reuse smem
      bf16* Lw = smem + wave * (64 * RLS);
      int cc0 = c0 - sel * D_DIM;
      int h   = cc0 / HD;
#pragma unroll
      for (int j = 0; j < NJ; ++j) {
        float bv = bias[c0 + j * 16 + l15];
#pragma unroll
        for (int i = 0; i < MI; ++i)
#pragma unroll
          for (int r = 0; r < 4; ++r)
            Lw[(i * 16 + quad * 4 + r) * RLS + j * 16 + l15] = (bf16)(acc[i][j][r] + bv);
      }
      __syncthreads();                 // wave-private, but be safe vs reorder
      // lane = local row
      int t = m0 + wm + lane;
      bf16x4 x[20];
#pragma unroll
      for (int a = 0; a < 20; ++a)
        x[a] = *(const bf16x4*)(Lw + lane * RLS + a * 4);
      const float* fp = rot + t * 40;
      float fr[40];
#pragma unroll
      for (int a = 0; a < 10; ++a) {
        float4 f4 = *(const float4*)(fp + a * 4);
        fr[a * 4] = f4.x; fr[a * 4 + 1] = f4.y; fr[a * 4 + 2] = f4.z; fr[a * 4 + 3] = f4.w;
      }
      const float sc = (sel == 0) ? 0.11180339887498949f : 1.0f;
      bf16* dst = ((sel == 0) ? Qh : Kh) + ((size_t)h * T_DIM + t) * HDP;
      // row chunk swizzle: logical 16B chunk g stored at g ^ ((t>>1)&3)
      int ksw = (t >> 1) & 3;
#pragma unroll
      for (int g = 0; g < 5; ++g) {
        bf16x8 c1, c2;
#pragma unroll
        for (int bb = 0; bb < 8; ++bb) {
          int a = g * 2 + (bb >> 2), b = bb & 3;
          float cs, sn;
          __sincosf(fr[a * 4 + b], &sn, &cs);
          cs *= sc; sn *= sc;
          float xa = (float)x[a][b], xb = (float)x[a + 10][b];
          c1[bb] = (bf16)(xa * cs - xb * sn);
          c2[bb] = (bf16)(xb * cs + xa * sn);
        }
        *(bf16x8*)(dst + (g ^ ksw) * 8)       = c1;
        *(bf16x8*)(dst + ((g + 5) ^ ksw) * 8) = c2;
      }
      bf16x8 z = {};
      *(bf16x8*)(dst + (10 ^ ksw) * 8) = z;
      *(bf16x8*)(dst + (11 ^ ksw) * 8) = z;
    } else {
      // ---- V scatter (transposed, t-major) ----
#pragma unroll
      for (int j = 0; j < NJ; ++j) {
        int c = c0 + j * 16 + l15;
        float bv = bias[c];
        int cc = c - 2 * D_DIM;
        int h = cc / HD, d = cc - h * HD;
        bf16* vrow = Vt + ((size_t)h * HD + d) * T_DIM;
#pragma unroll
        for (int i = 0; i < MI; ++i) {
          int t0 = m0 + wm + i * 16 + quad * 4;
          bf16x4 pv = {(bf16)(acc[i][j][0] + bv), (bf16)(acc[i][j][1] + bv),
                       (bf16)(acc[i][j][2] + bv), (bf16)(acc[i][j][3] + bv)};
          *(bf16x4*)(vrow + t0) = pv;
        }
      }
    }
  } else {
    float* out = (float*)out0;
#pragma unroll
    for (int j = 0; j < NJ; ++j) {
      int col = n0 + wn + j * 16 + l15;
      float bv = bias[col];
#pragma unroll
      for (int i = 0; i < MI; ++i)
#pragma unroll
        for (int r = 0; r < 4; ++r) {
          int row = m0 + wm + i * 16 + quad * 4 + r;
          out[(size_t)row * N + col] = acc[i][j][r] + bv;
        }
    }
  }
}

// ---------------------------------------------------------------------------
// K3: attention. Grid 1024 XCD-swizzled blocks (lin%8 groups share K/V L2).
// K/V staged via global_load_lds into double buffers; one barrier per QK
// chunk; V(0) prefetch issued during the last QK chunk and drains behind the
// softmax VALU stretch. V chunks XOR-swizzled (chunk ^ (d&7)). Qh/Kh rows
// arrive chunk-swizzled by ((t>>1)&3) (produced in K1); qf/kb deswizzle.
// R2: s_setprio(1) around MFMA clusters (blocks independent, 2/CU).
// ---------------------------------------------------------------------------
__global__ __launch_bounds__(256, 2) void attn_kernel(
    const bf16* __restrict__ Qh, const bf16* __restrict__ Kh,
    const bf16* __restrict__ Vt, bf16* __restrict__ out)
{
  // KV double buffers 2 x 24576 B (K [128][96] / V [80][128]); P 17408 B
  __shared__ __align__(16) char smem[66560];
  bf16* KV[2] = {(bf16*)smem, (bf16*)(smem + 24576)};
  bf16* Pl    = (bf16*)(smem + 49152);

  int lin  = blockIdx.x;
  int g    = lin & 127;        // (seg,head) group
  int tile = lin >> 7;         // 0..7
  int h    = g & 15;
  int seg  = g >> 4;
  int seg0 = seg * SEG;
  int t0   = seg0 + tile * 64;

  int tid  = threadIdx.x;
  int wave = tid >> 6;
  int lane = tid & 63;
  int l15 = lane & 15, quad = lane >> 4, q8 = quad * 8;
  int qs8 = ((quad ^ ((l15 >> 1) & 3)) * 8);   // Qh/Kh chunk deswizzle
  int tw = t0 + wave * 16;

  const bf16* khbase = Kh + ((size_t)h * T_DIM + seg0) * HDP;
  const bf16* vtbase = Vt + (size_t)h * HD * T_DIM + seg0;

  auto issueK = [&](int kc, bf16* buf) {
    const bf16* src = khbase + (size_t)kc * (128 * HDP);
#pragma unroll
    for (int i = 0; i < 6; ++i)
      gload16(src + (i * 256 + tid) * 8, buf + (i * 256 + tid) * 8);
  };
  auto issueV = [&](int kc, bf16* buf) {
    const bf16* src = vtbase + kc * 128;
#pragma unroll
    for (int i = 0; i < 5; ++i) {
      int idx = i * 256 + tid;            // 0..1279
      int d = idx >> 4, ch = idx & 15;
      int chg = ch ^ (d & 7);             // XOR source-chunk swizzle
      gload16(src + (size_t)d * T_DIM + chg * 8, buf + idx * 8);
    }
  };

  issueK(0, KV[0]);

  bf16x8 qf[3];
  {
    const bf16* qbase = Qh + ((size_t)h * T_DIM + tw + l15) * HDP + qs8;
#pragma unroll
    for (int kk = 0; kk < 3; ++kk) qf[kk] = *(const bf16x8*)(qbase + kk * 32);
  }

  // ---- Phase A: S = Q K^T, 4 chunks of 128 keys, 1 barrier/chunk ----
  f32x4 S[4][8];
  for (int kc = 0; kc < 4; ++kc) {
    bf16* buf = KV[kc & 1];
    __syncthreads();                       // drains DMA(kc) + prior reads
    if (kc < 3) issueK(kc + 1, KV[(kc & 1) ^ 1]);
    else        issueV(0, KV[0]);          // KV[0] free (last read chunk 2)
    __builtin_amdgcn_s_setprio(1);
#pragma unroll
    for (int j = 0; j < 8; ++j) {
      f32x4 acc = {0.f, 0.f, 0.f, 0.f};
      const bf16* kb = buf + (j * 16 + l15) * HDP + qs8;
#pragma unroll
      for (int kk = 0; kk < 3; ++kk)
        acc = __builtin_amdgcn_mfma_f32_16x16x32_bf16(qf[kk], *(const bf16x8*)(kb + kk * 32), acc, 0, 0, 0);
      S[kc][j] = acc;
    }
    __builtin_amdgcn_s_setprio(0);
  }

  // ---- Softmax (exact; scale pre-folded into Q). V(0) in flight. ----
  float vsum[4];
#pragma unroll
  for (int r = 0; r < 4; ++r) {
    float m = -1e30f;
#pragma unroll
    for (int kc = 0; kc < 4; ++kc)
#pragma unroll
      for (int j = 0; j < 8; ++j) m = fmaxf(m, S[kc][j][r]);
    for (int off = 1; off < 16; off <<= 1) m = fmaxf(m, __shfl_xor(m, off));
    float s = 0.f;
#pragma unroll
    for (int kc = 0; kc < 4; ++kc)
#pragma unroll
      for (int j = 0; j < 8; ++j) {
        float e = __expf(S[kc][j][r] - m);
        S[kc][j][r] = e;
        s += e;
      }
    for (int off = 1; off < 16; off <<= 1) s += __shfl_xor(s, off);
    vsum[r] = s;
  }

  // ---- Phase B: O = P V, 4 chunks, V prefetched one chunk ahead ----
  f32x4 O[5];
#pragma unroll
  for (int n = 0; n < 5; ++n) O[n] = (f32x4){0.f, 0.f, 0.f, 0.f};
  bf16* Plw = Pl + wave * (16 * VLP);

  for (int kc = 0; kc < 4; ++kc) {
    bf16* vbuf = KV[kc & 1];
    __syncthreads();                       // drains V(kc); prior MFMA reads done
    if (kc < 3) issueV(kc + 1, KV[(kc & 1) ^ 1]);
#pragma unroll
    for (int j = 0; j < 8; ++j)
#pragma unroll
      for (int r = 0; r < 4; ++r)
        Plw[(quad * 4 + r) * VLP + j * 16 + l15] = (bf16)S[kc][j][r];
    __syncthreads();                       // P visible
    __builtin_amdgcn_s_setprio(1);
#pragma unroll
    for (int ks = 0; ks < 4; ++ks) {
      bf16x8 pa = *(const bf16x8*)(Plw + l15 * VLP + ks * 32 + q8);
#pragma unroll
      for (int n = 0; n < 5; ++n) {
        int d = n * 16 + l15;
        // global chunk (ks*4+quad) lives at LDS chunk ^(d&7)
        int chl = (ks * 4 + quad) ^ (d & 7);
        bf16x8 vb = *(const bf16x8*)(vbuf + d * 128 + chl * 8);
        O[n] = __builtin_amdgcn_mfma_f32_16x16x32_bf16(pa, vb, O[n], 0, 0, 0);
      }
    }
    __builtin_amdgcn_s_setprio(0);
  }

#pragma unroll
  for (int n = 0; n < 5; ++n)
#pragma unroll
    for (int r = 0; r < 4; ++r) {
      int row = tw + quad * 4 + r;
      int col = h * HD + n * 16 + l15;
      out[(size_t)row * D_DIM + col] = (bf16)(O[n][r] / vsum[r]);
    }
}

// ---------------------------------------------------------------------------
extern "C" void kernel_launch(void* const* d_in, const int* in_sizes, int n_in,
                              void* d_out, int out_size, void* d_ws, size_t ws_size,
                              hipStream_t stream)
{
  const float* hidden = (const float*)d_in[0];
  // d_in[1]: cu_seqlens (int32) — fixed 8x512 segments, handled structurally
  const float* rot    = (const float*)d_in[2];
  const float* qkv_w  = (const float*)d_in[3];
  const float* qkv_b  = (const float*)d_in[4];
  const float* proj_w = (const float*)d_in[5];
  const float* proj_b = (const float*)d_in[6];
  float* out = (float*)d_out;

  char* ws = (char*)d_ws;
  bf16* qkvw_bf  = (bf16*)(ws);              //  9,830,400 B [3840][1280]
  bf16* projw_bf = (bf16*)(ws +  9830400);   //  3,276,800 B [1280][1280]
  bf16* hid_bf   = (bf16*)(ws + 13107200);   // 10,485,760 B [4096][1280]
  bf16* attn     = (bf16*)(ws + 13107200);   // reuses hid_bf (dead after K1)
  bf16* Qh       = (bf16*)(ws + 23592960);   // 12,582,912 B [16][4096][96]
  bf16* Kh       = (bf16*)(ws + 36175872);   // 12,582,912 B
  bf16* Vt       = (bf16*)(ws + 48758784);   // 10,485,760 B [16][80][4096]
                                             // total 59,244,544 B

  cvt_all<<<dim3(11520), dim3(256), 0, stream>>>(
      hidden, qkv_w, proj_w, hid_bf, qkvw_bf, projw_bf);
  // K1: qkv GEMM + fused rope, 32x24 tiles of 128x160, XCD = nt%8 mapping
  gemm128<0, 128, 160><<<dim3(768), dim3(256), 0, stream>>>(
      hid_bf, qkvw_bf, qkv_b, rot, (void*)Qh, Kh, Vt, 3840, 1280, 24);
  // K3: block-diagonal attention, XCD-swizzled linear grid
  attn_kernel<<<dim3(1024), dim3(256), 0, stream>>>(Qh, Kh, Vt, attn);
  // K4: proj GEMM, 64x10 tiles of 64x128, fp32 out, A-sharing swizzle
  gemm128<1, 64, 128><<<dim3(640), dim3(256), 0, stream>>>(
      attn, projw_bf, proj_b, nullptr, (void*)out, nullptr, nullptr, 1280, 1280, 10);
}

// Round 4
// 205.412 us; speedup vs baseline: 5.4092x; 5.4092x over previous
//
#include <hip/hip_runtime.h>
#include <hip/hip_bf16.h>

// ---------------------------------------------------------------------------
// Qwen2VL SDPA attention block, MI355X/gfx950. fp32 in/out, bf16 MFMA inside.
// T=4096, D=1280, H=16, HD=80, 8 segments of 512 (block-diagonal attention).
// Pipeline: [C]  convert hidden/qkv_w/proj_w fp32->bf16 (one fused kernel)
//           [K1] qkv GEMM (128x160 tile) with FUSED ROPE epilogue
//                -> Qh/Kh [h][t][96], V -> Vt[h][d][t]
//           [K3] attention: K/V DMA double-buffered, exact softmax
//           [K4] out = attn @ proj_w^T + proj_b (BM=64, A-sharing XCD swizzle)
// R1: chunk XOR-swizzle -> bank conflicts 4.4M -> 0 (kept). -4% only.
// R2: XCD mapping (FETCH at floor) + 4/CU capacity: flat => schedule-bound
//     (full vmcnt(0) drain per K-step).
// R3: counted-vmcnt attempt FAILED: WRITE_SIZE 4.1 GB = acc spilled to
//     scratch (live ranges stretched + launch_bounds(256,4) 128-reg cap).
// R4: counted-vmcnt done right:
//     - 4-slot LDS ring; at iter kt: issue tile kt+2, s_waitcnt vmcnt(2c)
//       (tiles kt+1,kt+2 in flight; wait targets tile kt issued 2 iters ago),
//       ONE s_barrier/iter (serves "tile kt ready" + "reads of kt-2 retired";
//       slot (kt+2)&3 last read at iter kt-2, sbar(kt-1) separates).
//     - uniform VMEM counts: B staged as 192 rows (32-row pad, clamped
//       in-bounds sources, never read) => every thread 5 loads (K1) / 3 (K4).
//     - R2's frag->MFMA body untouched; launch_bounds(256,2) => 256-reg
//       budget, no spill. LDS 81920 B => 2 blocks/CU (ILP replaces TLP).
// ---------------------------------------------------------------------------

#define T_DIM 4096
#define D_DIM 1280
#define NH    16
#define HD    80
#define HDP   96      // head dim padded to 3x32 for K=32 MFMA steps
#define SEG   512
#define VLP   136     // P LDS row stride (pad off pow2)
#define RLS   80      // rope-epilogue LDS row stride

typedef __bf16 bf16;
typedef bf16  bf16x4 __attribute__((ext_vector_type(4)));
typedef bf16  bf16x8 __attribute__((ext_vector_type(8)));
typedef float f32x4  __attribute__((ext_vector_type(4)));

#define SBAR()    asm volatile("s_barrier" ::: "memory")
#define WAITVM(n) asm volatile("s_waitcnt vmcnt(" #n ")" ::: "memory")

__device__ __forceinline__ void gload16(const bf16* g, bf16* l) {
  __builtin_amdgcn_global_load_lds(
      (const __attribute__((address_space(1))) void*)g,
      (__attribute__((address_space(3))) void*)l, 16, 0, 0);
}

// ---------------------------------------------------------------------------
// Fused fp32->bf16 convert of hidden (1310720 f4), qkv_w (1228800 f4),
// proj_w (409600 f4). Grid covers 2949120 float4 groups.
// ---------------------------------------------------------------------------
__global__ __launch_bounds__(256) void cvt_all(
    const float* __restrict__ hid, const float* __restrict__ qw,
    const float* __restrict__ pw, bf16* __restrict__ hb,
    bf16* __restrict__ qwb, bf16* __restrict__ pwb)
{
  int i = blockIdx.x * 256 + threadIdx.x;
  const float* src; bf16* dst; int off;
  if (i < 1310720)      { src = hid; dst = hb;  off = i; }
  else if (i < 2539520) { src = qw;  dst = qwb; off = i - 1310720; }
  else                  { src = pw;  dst = pwb; off = i - 2539520; }
  float4 v = ((const float4*)src)[off];
  ((bf16x4*)dst)[off] = (bf16x4){(bf16)v.x, (bf16)v.y, (bf16)v.z, (bf16)v.w};
}

// ---------------------------------------------------------------------------
// BMxBN-tile GEMM: C = A[M,K] @ W[N,K]^T + bias. BK=32, 4 waves (2x2), each
// wave (BM/2)x(BN/2). 4-deep LDS ring staged via global_load_lds width=16.
// LDS rows are 32 bf16 (64 B = 4 chunks of 16 B); chunk c of row r holds
// logical chunk c ^ ((r>>1)&3)  [pre-swizzled global source, deswizzled on
// the frag read] -> 2-way banks.
// K-loop (R4): issue(kt+2) -> vmcnt(2c) -> sbar -> frags+MFMA. One barrier
// per iter; never drains in-flight prefetch.
// EPI=0 (BM=128,BN=160): wave-half = one head. Q/K: C-tile -> wave LDS ->
//   rope -> [h][t][96] chunks XOR-swizzled by ((t>>1)&3). V: Vt[h][d][T].
//   Grid: mt=lin/24, nt=lin%24 (XCD = nt%8, W-tile L2-resident).
// EPI=1: A-sharing swizzle; fp32 store.
// ---------------------------------------------------------------------------
template <int EPI, int BM, int BN>
__global__ __launch_bounds__(256, 2) void gemm128(
    const bf16* __restrict__ A, const bf16* __restrict__ W,
    const float* __restrict__ bias, const float* __restrict__ rot,
    void* __restrict__ out0, bf16* __restrict__ Kh, bf16* __restrict__ Vt,
    int N, int K, int tiles_n)
{
  constexpr int MI = BM / 32;               // m-frags per wave
  constexpr int NJ = BN / 32;               // n-frags per wave
  constexpr int BNP = (BN == 160) ? 192 : BN;   // staged B rows (pad->uniform)
  constexpr int ASLOT = BM * 32;            // elems per A slot
  constexpr int BSLOT = BNP * 32;           // elems per B slot
  constexpr int STAGE = 4 * (ASLOT + BSLOT);
  constexpr int EPIB  = (EPI == 0) ? 4 * 64 * RLS : 0;
  constexpr int LDSZ  = (STAGE > EPIB ? STAGE : EPIB);
  __shared__ __align__(16) bf16 smem[LDSZ];
  bf16* As = smem;                          // 4 slots
  bf16* Bs = smem + 4 * ASLOT;              // 4 slots

  int tid  = threadIdx.x;
  int wave = tid >> 6, lane = tid & 63;
  int l15 = lane & 15, quad = lane >> 4;
  // deswizzled chunk offset for frag reads: row bits1..2 == l15 bits1..2
  int q8s = ((quad ^ ((l15 >> 1) & 3)) * 8);
  int mt, nt;
  if (EPI == 0) {
    // XCD-locality mapping: lin = mt*tiles_n + nt, tiles_n % 8 == 0
    // => XCD(lin%8) = nt%8: same-W blocks co-located, W-tile L2-resident.
    mt = blockIdx.x / tiles_n;
    nt = blockIdx.x % tiles_n;
  } else {
    // A-sharing swizzle: lin = nt*tiles_m + mt -> lin%8 == mt%8 (same XCD)
    int tiles_m = gridDim.x / tiles_n;
    mt = blockIdx.x % tiles_m;
    nt = blockIdx.x / tiles_m;
  }
  int m0 = mt * BM, n0 = nt * BN;
  int wm = (wave >> 1) * (BM / 2), wn = (wave & 1) * (BN / 2);

  int er  = tid >> 2;
  // source chunk XOR-pre-swizzle: LDS dest (tid*16B) is linear, so physical
  // chunk (tid&3) of row er must hold logical chunk (tid&3)^((er>>1)&3).
  int ec8 = (((tid & 3) ^ ((tid >> 3) & 3)) * 8);
  const bf16* ga = A + (size_t)(m0 + er) * K + ec8;
  const bf16* gb = W + (size_t)(n0 + er) * K + ec8;

  // One stage batch = (BM + BNP)/64 VMEM instrs per thread, uniform across
  // waves. K1: 2+3=5.  K4: 1+2=3.
  auto issueN = [&](int k, int s) {
    bf16* la = As + s * ASLOT + tid * 8;
    bf16* lb = Bs + s * BSLOT + tid * 8;
#pragma unroll
    for (int i = 0; i < BM / 64; ++i)
      gload16(ga + (size_t)i * 64 * K + k, la + i * 2048);
    if (BN == 160) {
      gload16(gb + k, lb);
      gload16(gb + (size_t)64 * K + k, lb + 2048);
      // rows 128..191: rows >=160 are pad; clamp source in-bounds (row-64),
      // dest goes to the never-read pad region. Count stays uniform.
      size_t o3 = (tid < 128) ? (size_t)128 * K : (size_t)64 * K;
      gload16(gb + o3 + k, lb + 4096);
    } else {
#pragma unroll
      for (int i = 0; i < BN / 64; ++i)
        gload16(gb + (size_t)i * 64 * K + k, lb + i * 2048);
    }
  };

  f32x4 acc[MI][NJ];
#pragma unroll
  for (int i = 0; i < MI; ++i)
#pragma unroll
    for (int j = 0; j < NJ; ++j) acc[i][j] = (f32x4){0.f, 0.f, 0.f, 0.f};

  int NK = K / 32;
  issueN(0, 0);
  issueN(32, 1);
  for (int kt = 0; kt < NK; ++kt) {
    int p = kt & 3;
    if (kt + 2 < NK) {
      issueN((kt + 2) * 32, (kt + 2) & 3);
      // tiles kt+1, kt+2 stay in flight; tile kt guaranteed landed
      if (BN == 160) { WAITVM(10); } else { WAITVM(6); }
    } else if (kt + 1 < NK) {
      if (BN == 160) { WAITVM(5); } else { WAITVM(3); }
    } else {
      WAITVM(0);
    }
    SBAR();
    bf16x8 af[MI], bfr[NJ];
#pragma unroll
    for (int i = 0; i < MI; ++i)
      af[i] = *(const bf16x8*)(As + p * ASLOT + (wm + i * 16 + l15) * 32 + q8s);
#pragma unroll
    for (int j = 0; j < NJ; ++j)
      bfr[j] = *(const bf16x8*)(Bs + p * BSLOT + (wn + j * 16 + l15) * 32 + q8s);
    __builtin_amdgcn_s_setprio(1);
#pragma unroll
    for (int i = 0; i < MI; ++i)
#pragma unroll
      for (int j = 0; j < NJ; ++j)
        acc[i][j] = __builtin_amdgcn_mfma_f32_16x16x32_bf16(af[i], bfr[j], acc[i][j], 0, 0, 0);
    __builtin_amdgcn_s_setprio(0);
  }

  if (EPI == 0) {
    bf16* Qh = (bf16*)out0;
    int c0  = n0 + wn;                 // wave's first col = head base
    int sel = c0 / D_DIM;              // 0=Q, 1=K, 2=V (block-uniform: BN=160 | 1280)
    if (sel < 2) {
      // ---- fused rope epilogue ----
      __syncthreads();                 // all frag reads done; reuse smem
      bf16* Lw = smem + wave * (64 * RLS);
      int cc0 = c0 - sel * D_DIM;
      int h   = cc0 / HD;
#pragma unroll
      for (int j = 0; j < NJ; ++j) {
        float bv = bias[c0 + j * 16 + l15];
#pragma unroll
        for (int i = 0; i < MI; ++i)
#pragma unroll
          for (int r = 0; r < 4; ++r)
            Lw[(i * 16 + quad * 4 + r) * RLS + j * 16 + l15] = (bf16)(acc[i][j][r] + bv);
      }
      __syncthreads();                 // wave-private, but be safe vs reorder
      // lane = local row
      int t = m0 + wm + lane;
      bf16x4 x[20];
#pragma unroll
      for (int a = 0; a < 20; ++a)
        x[a] = *(const bf16x4*)(Lw + lane * RLS + a * 4);
      const float* fp = rot + t * 40;
      float fr[40];
#pragma unroll
      for (int a = 0; a < 10; ++a) {
        float4 f4 = *(const float4*)(fp + a * 4);
        fr[a * 4] = f4.x; fr[a * 4 + 1] = f4.y; fr[a * 4 + 2] = f4.z; fr[a * 4 + 3] = f4.w;
      }
      const float sc = (sel == 0) ? 0.11180339887498949f : 1.0f;
      bf16* dst = ((sel == 0) ? Qh : Kh) + ((size_t)h * T_DIM + t) * HDP;
      // row chunk swizzle: logical 16B chunk g stored at g ^ ((t>>1)&3)
      int ksw = (t >> 1) & 3;
#pragma unroll
      for (int g = 0; g < 5; ++g) {
        bf16x8 c1, c2;
#pragma unroll
        for (int bb = 0; bb < 8; ++bb) {
          int a = g * 2 + (bb >> 2), b = bb & 3;
          float cs, sn;
          __sincosf(fr[a * 4 + b], &sn, &cs);
          cs *= sc; sn *= sc;
          float xa = (float)x[a][b], xb = (float)x[a + 10][b];
          c1[bb] = (bf16)(xa * cs - xb * sn);
          c2[bb] = (bf16)(xb * cs + xa * sn);
        }
        *(bf16x8*)(dst + (g ^ ksw) * 8)       = c1;
        *(bf16x8*)(dst + ((g + 5) ^ ksw) * 8) = c2;
      }
      bf16x8 z = {};
      *(bf16x8*)(dst + (10 ^ ksw) * 8) = z;
      *(bf16x8*)(dst + (11 ^ ksw) * 8) = z;
    } else {
      // ---- V scatter (transposed, t-major) ----
#pragma unroll
      for (int j = 0; j < NJ; ++j) {
        int c = c0 + j * 16 + l15;
        float bv = bias[c];
        int cc = c - 2 * D_DIM;
        int h = cc / HD, d = cc - h * HD;
        bf16* vrow = Vt + ((size_t)h * HD + d) * T_DIM;
#pragma unroll
        for (int i = 0; i < MI; ++i) {
          int t0 = m0 + wm + i * 16 + quad * 4;
          bf16x4 pv = {(bf16)(acc[i][j][0] + bv), (bf16)(acc[i][j][1] + bv),
                       (bf16)(acc[i][j][2] + bv), (bf16)(acc[i][j][3] + bv)};
          *(bf16x4*)(vrow + t0) = pv;
        }
      }
    }
  } else {
    float* out = (float*)out0;
#pragma unroll
    for (int j = 0; j < NJ; ++j) {
      int col = n0 + wn + j * 16 + l15;
      float bv = bias[col];
#pragma unroll
      for (int i = 0; i < MI; ++i)
#pragma unroll
        for (int r = 0; r < 4; ++r) {
          int row = m0 + wm + i * 16 + quad * 4 + r;
          out[(size_t)row * N + col] = acc[i][j][r] + bv;
        }
    }
  }
}

// ---------------------------------------------------------------------------
// K3: attention. Grid 1024 XCD-swizzled blocks (lin%8 groups share K/V L2).
// K/V staged via global_load_lds into double buffers; one barrier per QK
// chunk; V(0) prefetch issued during the last QK chunk and drains behind the
// softmax VALU stretch. V chunks XOR-swizzled (chunk ^ (d&7)). Qh/Kh rows
// arrive chunk-swizzled by ((t>>1)&3) (produced in K1); qf/kb deswizzle.
// s_setprio(1) around MFMA clusters (blocks independent, 2/CU).
// ---------------------------------------------------------------------------
__global__ __launch_bounds__(256, 2) void attn_kernel(
    const bf16* __restrict__ Qh, const bf16* __restrict__ Kh,
    const bf16* __restrict__ Vt, bf16* __restrict__ out)
{
  // KV double buffers 2 x 24576 B (K [128][96] / V [80][128]); P 17408 B
  __shared__ __align__(16) char smem[66560];
  bf16* KV[2] = {(bf16*)smem, (bf16*)(smem + 24576)};
  bf16* Pl    = (bf16*)(smem + 49152);

  int lin  = blockIdx.x;
  int g    = lin & 127;        // (seg,head) group
  int tile = lin >> 7;         // 0..7
  int h    = g & 15;
  int seg  = g >> 4;
  int seg0 = seg * SEG;
  int t0   = seg0 + tile * 64;

  int tid  = threadIdx.x;
  int wave = tid >> 6;
  int lane = tid & 63;
  int l15 = lane & 15, quad = lane >> 4, q8 = quad * 8;
  int qs8 = ((quad ^ ((l15 >> 1) & 3)) * 8);   // Qh/Kh chunk deswizzle
  int tw = t0 + wave * 16;

  const bf16* khbase = Kh + ((size_t)h * T_DIM + seg0) * HDP;
  const bf16* vtbase = Vt + (size_t)h * HD * T_DIM + seg0;

  auto issueK = [&](int kc, bf16* buf) {
    const bf16* src = khbase + (size_t)kc * (128 * HDP);
#pragma unroll
    for (int i = 0; i < 6; ++i)
      gload16(src + (i * 256 + tid) * 8, buf + (i * 256 + tid) * 8);
  };
  auto issueV = [&](int kc, bf16* buf) {
    const bf16* src = vtbase + kc * 128;
#pragma unroll
    for (int i = 0; i < 5; ++i) {
      int idx = i * 256 + tid;            // 0..1279
      int d = idx >> 4, ch = idx & 15;
      int chg = ch ^ (d & 7);             // XOR source-chunk swizzle
      gload16(src + (size_t)d * T_DIM + chg * 8, buf + idx * 8);
    }
  };

  issueK(0, KV[0]);

  bf16x8 qf[3];
  {
    const bf16* qbase = Qh + ((size_t)h * T_DIM + tw + l15) * HDP + qs8;
#pragma unroll
    for (int kk = 0; kk < 3; ++kk) qf[kk] = *(const bf16x8*)(qbase + kk * 32);
  }

  // ---- Phase A: S = Q K^T, 4 chunks of 128 keys, 1 barrier/chunk ----
  f32x4 S[4][8];
  for (int kc = 0; kc < 4; ++kc) {
    bf16* buf = KV[kc & 1];
    __syncthreads();                       // drains DMA(kc) + prior reads
    if (kc < 3) issueK(kc + 1, KV[(kc & 1) ^ 1]);
    else        issueV(0, KV[0]);          // KV[0] free (last read chunk 2)
    __builtin_amdgcn_s_setprio(1);
#pragma unroll
    for (int j = 0; j < 8; ++j) {
      f32x4 acc = {0.f, 0.f, 0.f, 0.f};
      const bf16* kb = buf + (j * 16 + l15) * HDP + qs8;
#pragma unroll
      for (int kk = 0; kk < 3; ++kk)
        acc = __builtin_amdgcn_mfma_f32_16x16x32_bf16(qf[kk], *(const bf16x8*)(kb + kk * 32), acc, 0, 0, 0);
      S[kc][j] = acc;
    }
    __builtin_amdgcn_s_setprio(0);
  }

  // ---- Softmax (exact; scale pre-folded into Q). V(0) in flight. ----
  float vsum[4];
#pragma unroll
  for (int r = 0; r < 4; ++r) {
    float m = -1e30f;
#pragma unroll
    for (int kc = 0; kc < 4; ++kc)
#pragma unroll
      for (int j = 0; j < 8; ++j) m = fmaxf(m, S[kc][j][r]);
    for (int off = 1; off < 16; off <<= 1) m = fmaxf(m, __shfl_xor(m, off));
    float s = 0.f;
#pragma unroll
    for (int kc = 0; kc < 4; ++kc)
#pragma unroll
      for (int j = 0; j < 8; ++j) {
        float e = __expf(S[kc][j][r] - m);
        S[kc][j][r] = e;
        s += e;
      }
    for (int off = 1; off < 16; off <<= 1) s += __shfl_xor(s, off);
    vsum[r] = s;
  }

  // ---- Phase B: O = P V, 4 chunks, V prefetched one chunk ahead ----
  f32x4 O[5];
#pragma unroll
  for (int n = 0; n < 5; ++n) O[n] = (f32x4){0.f, 0.f, 0.f, 0.f};
  bf16* Plw = Pl + wave * (16 * VLP);

  for (int kc = 0; kc < 4; ++kc) {
    bf16* vbuf = KV[kc & 1];
    __syncthreads();                       // drains V(kc); prior MFMA reads done
    if (kc < 3) issueV(kc + 1, KV[(kc & 1) ^ 1]);
#pragma unroll
    for (int j = 0; j < 8; ++j)
#pragma unroll
      for (int r = 0; r < 4; ++r)
        Plw[(quad * 4 + r) * VLP + j * 16 + l15] = (bf16)S[kc][j][r];
    __syncthreads();                       // P visible
    __builtin_amdgcn_s_setprio(1);
#pragma unroll
    for (int ks = 0; ks < 4; ++ks) {
      bf16x8 pa = *(const bf16x8*)(Plw + l15 * VLP + ks * 32 + q8);
#pragma unroll
      for (int n = 0; n < 5; ++n) {
        int d = n * 16 + l15;
        // global chunk (ks*4+quad) lives at LDS chunk ^(d&7)
        int chl = (ks * 4 + quad) ^ (d & 7);
        bf16x8 vb = *(const bf16x8*)(vbuf + d * 128 + chl * 8);
        O[n] = __builtin_amdgcn_mfma_f32_16x16x32_bf16(pa, vb, O[n], 0, 0, 0);
      }
    }
    __builtin_amdgcn_s_setprio(0);
  }

#pragma unroll
  for (int n = 0; n < 5; ++n)
#pragma unroll
    for (int r = 0; r < 4; ++r) {
      int row = tw + quad * 4 + r;
      int col = h * HD + n * 16 + l15;
      out[(size_t)row * D_DIM + col] = (bf16)(O[n][r] / vsum[r]);
    }
}

// ---------------------------------------------------------------------------
extern "C" void kernel_launch(void* const* d_in, const int* in_sizes, int n_in,
                              void* d_out, int out_size, void* d_ws, size_t ws_size,
                              hipStream_t stream)
{
  const float* hidden = (const float*)d_in[0];
  // d_in[1]: cu_seqlens (int32) — fixed 8x512 segments, handled structurally
  const float* rot    = (const float*)d_in[2];
  const float* qkv_w  = (const float*)d_in[3];
  const float* qkv_b  = (const float*)d_in[4];
  const float* proj_w = (const float*)d_in[5];
  const float* proj_b = (const float*)d_in[6];
  float* out = (float*)d_out;

  char* ws = (char*)d_ws;
  bf16* qkvw_bf  = (bf16*)(ws);              //  9,830,400 B [3840][1280]
  bf16* projw_bf = (bf16*)(ws +  9830400);   //  3,276,800 B [1280][1280]
  bf16* hid_bf   = (bf16*)(ws + 13107200);   // 10,485,760 B [4096][1280]
  bf16* attn     = (bf16*)(ws + 13107200);   // reuses hid_bf (dead after K1)
  bf16* Qh       = (bf16*)(ws + 23592960);   // 12,582,912 B [16][4096][96]
  bf16* Kh       = (bf16*)(ws + 36175872);   // 12,582,912 B
  bf16* Vt       = (bf16*)(ws + 48758784);   // 10,485,760 B [16][80][4096]
                                             // total 59,244,544 B

  cvt_all<<<dim3(11520), dim3(256), 0, stream>>>(
      hidden, qkv_w, proj_w, hid_bf, qkvw_bf, projw_bf);
  // K1: qkv GEMM + fused rope, 32x24 tiles of 128x160, XCD = nt%8 mapping
  gemm128<0, 128, 160><<<dim3(768), dim3(256), 0, stream>>>(
      hid_bf, qkvw_bf, qkv_b, rot, (void*)Qh, Kh, Vt, 3840, 1280, 24);
  // K3: block-diagonal attention, XCD-swizzled linear grid
  attn_kernel<<<dim3(1024), dim3(256), 0, stream>>>(Qh, Kh, Vt, attn);
  // K4: proj GEMM, 64x10 tiles of 64x128, fp32 out, A-sharing swizzle
  gemm128<1, 64, 128><<<dim3(640), dim3(256), 0, stream>>>(
      attn, projw_bf, proj_b, nullptr, (void*)out, nullptr, nullptr, 1280, 1280, 10);
}